// Round 1
// baseline (77.571 us; speedup 1.0000x reference)
//
#include <hip/hip_runtime.h>
#include <hip/hip_bf16.h>

#define HWDIM 512
#define NWIN 50        // windows per dim: (512-20)/10 + 1
#define WIN 20
#define STRIDEW 10
#define NBC 48         // B*C = 16*3
#define EPSV 1e-5f

// ws layout: acc[0..95]: (ssq, total) pairs per (b,ch)
__global__ void zero_kernel(float* acc) {
    int t = threadIdx.x;
    if (t < 2 * NBC) acc[t] = 0.0f;
}

__global__ __launch_bounds__(256) void win_kernel(const float* __restrict__ Cp,
                                                  const float* __restrict__ Ep,
                                                  const float* __restrict__ Mp,
                                                  float* __restrict__ acc) {
    int blk = blockIdx.x;          // 0 .. 48*50-1
    int bc  = blk / NWIN;          // plane index
    int wy  = blk % NWIN;          // window row
    size_t base = (size_t)bc * (HWDIM * HWDIM) + (size_t)(wy * STRIDEW) * HWDIM;
    const float* cp = Cp + base;
    const float* ep = Ep + base;
    const float* mp = Mp + base;

    int lane = threadIdx.x & 63;
    int wave = threadIdx.x >> 6;

    float ssq = 0.0f, tot = 0.0f;

    for (int wx = wave; wx < NWIN; wx += 4) {
        int cbase = wx * STRIDEW;
        float s_cc = 0.0f, s_ce = 0.0f, s_ee = 0.0f;
        #pragma unroll
        for (int ii = 0; ii < 7; ++ii) {
            int i = lane + ii * 64;
            if (i < WIN * WIN) {
                int r   = i / WIN;
                int col = i - r * WIN;
                int off = r * HWDIM + cbase + col;
                float c = cp[off];
                float e = ep[off];
                float m = mp[off];
                s_cc = fmaf(m * c, c, s_cc);
                s_ce = fmaf(m * c, e, s_ce);
                s_ee = fmaf(m * e, e, s_ee);
            }
        }
        // full-wave butterfly reduce (64 lanes)
        #pragma unroll
        for (int d = 1; d < 64; d <<= 1) {
            s_cc += __shfl_xor(s_cc, d);
            s_ce += __shfl_xor(s_ce, d);
            s_ee += __shfl_xor(s_ee, d);
        }
        float a2v = (s_ee > EPSV) ? (s_ce * s_ce / s_ee) : 0.0f;
        ssq += s_cc - a2v;
        tot += s_cc;
    }

    __shared__ float sred[8];
    if (lane == 0) { sred[wave] = ssq; sred[4 + wave] = tot; }
    __syncthreads();
    if (threadIdx.x == 0) {
        float S = sred[0] + sred[1] + sred[2] + sred[3];
        float T = sred[4] + sred[5] + sred[6] + sred[7];
        atomicAdd(&acc[bc * 2 + 0], S);
        atomicAdd(&acc[bc * 2 + 1], T);
    }
}

__global__ void final_kernel(const float* __restrict__ acc, float* __restrict__ out) {
    int lane = threadIdx.x;
    float r = 0.0f;
    if (lane < NBC) {
        float S = acc[lane * 2 + 0];
        float T = acc[lane * 2 + 1];
        r = S / T;
    }
    #pragma unroll
    for (int d = 1; d < 64; d <<= 1) r += __shfl_xor(r, d);
    if (lane == 0) out[0] = r / (float)NBC;
}

extern "C" void kernel_launch(void* const* d_in, const int* in_sizes, int n_in,
                              void* d_out, int out_size, void* d_ws, size_t ws_size,
                              hipStream_t stream) {
    const float* correct  = (const float*)d_in[0];
    const float* estimate = (const float*)d_in[1];
    const float* mask     = (const float*)d_in[2];
    float* out = (float*)d_out;
    float* acc = (float*)d_ws;

    zero_kernel<<<1, 128, 0, stream>>>(acc);
    win_kernel<<<NBC * NWIN, 256, 0, stream>>>(correct, estimate, mask, acc);
    final_kernel<<<1, 64, 0, stream>>>(acc, out);
}

// Round 2
// 35.728 us; speedup vs baseline: 2.1712x; 2.1712x over previous
//
#include <hip/hip_runtime.h>
#include <hip/hip_bf16.h>

#define HWDIM 512
#define NWIN 50        // windows per dim: (512-20)/10 + 1
#define NT 51          // 10x10 tiles per dim covering rows/cols 0..509
#define NBC 48         // B*C = 16*3
#define EPSV 1e-5f

// ---------------------------------------------------------------------------
// Pass 1: per-(plane, 10-row stripe) tile sums.
// Block = 256 threads; thread t owns columns 2t, 2t+1 across the 10 rows.
// Tile boundaries are at multiples of 10 (even), so a float2 never straddles
// a tile. Threads 5*tx .. 5*tx+4 cover tile tx (tx = 0..50); thread 255
// (cols 510/511) is outside all windows and is ignored in the reduce.
// Output: tiles[(blk*NT + tx)*3 + {0,1,2}] = (sum m*c*c, m*c*e, m*e*e).
// ---------------------------------------------------------------------------
__global__ __launch_bounds__(256) void tile_kernel(const float* __restrict__ C,
                                                   const float* __restrict__ E,
                                                   const float* __restrict__ M,
                                                   float* __restrict__ tiles) {
    int blk   = blockIdx.x;        // plane*NT + ty
    int plane = blk / NT;
    int ty    = blk % NT;
    int t     = threadIdx.x;

    size_t rowbase = ((size_t)plane * HWDIM + (size_t)ty * 10) * HWDIM;
    const float2* c2 = (const float2*)(C + rowbase);
    const float2* e2 = (const float2*)(E + rowbase);
    const float2* m2 = (const float2*)(M + rowbase);

    float s_cc = 0.0f, s_ce = 0.0f, s_ee = 0.0f;
    #pragma unroll
    for (int r = 0; r < 10; ++r) {
        int idx = r * 256 + t;     // float2 index within the stripe
        float2 c = c2[idx];
        float2 e = e2[idx];
        float2 m = m2[idx];
        float mc0 = m.x * c.x, mc1 = m.y * c.y;
        float me0 = m.x * e.x, me1 = m.y * e.y;
        s_cc = fmaf(mc0, c.x, s_cc); s_cc = fmaf(mc1, c.y, s_cc);
        s_ce = fmaf(mc0, e.x, s_ce); s_ce = fmaf(mc1, e.y, s_ce);
        s_ee = fmaf(me0, e.x, s_ee); s_ee = fmaf(me1, e.y, s_ee);
    }

    __shared__ float lds[3 * 256];
    lds[t]       = s_cc;
    lds[256 + t] = s_ce;
    lds[512 + t] = s_ee;
    __syncthreads();

    if (t < NT * 3) {              // 153 threads: one per (tile, component)
        int tx = t / 3, comp = t % 3;
        const float* p = lds + comp * 256 + 5 * tx;
        float s = p[0] + p[1] + p[2] + p[3] + p[4];
        tiles[((size_t)blk * NT + tx) * 3 + comp] = s;
    }
}

// ---------------------------------------------------------------------------
// Pass 2: per-plane window combine. Window (wy,wx) = 4 tiles.
// ---------------------------------------------------------------------------
__global__ __launch_bounds__(256) void window_kernel(const float* __restrict__ tiles,
                                                     float* __restrict__ acc) {
    int plane = blockIdx.x;
    const float* tp = tiles + (size_t)plane * NT * NT * 3;

    float ssq = 0.0f, tot = 0.0f;
    for (int w = threadIdx.x; w < NWIN * NWIN; w += 256) {
        int wy = w / NWIN, wx = w % NWIN;
        const float* t00 = tp + ((size_t)wy * NT + wx) * 3;
        const float* t10 = t00 + (size_t)NT * 3;
        float s_cc = t00[0] + t00[3] + t10[0] + t10[3];
        float s_ce = t00[1] + t00[4] + t10[1] + t10[4];
        float s_ee = t00[2] + t00[5] + t10[2] + t10[5];
        float a2v = (s_ee > EPSV) ? (s_ce * s_ce / s_ee) : 0.0f;
        ssq += s_cc - a2v;
        tot += s_cc;
    }

    // wave butterfly + cross-wave LDS reduce
    #pragma unroll
    for (int d = 1; d < 64; d <<= 1) {
        ssq += __shfl_xor(ssq, d);
        tot += __shfl_xor(tot, d);
    }
    __shared__ float sr[8];
    int lane = threadIdx.x & 63, wave = threadIdx.x >> 6;
    if (lane == 0) { sr[wave] = ssq; sr[4 + wave] = tot; }
    __syncthreads();
    if (threadIdx.x == 0) {
        float S = sr[0] + sr[1] + sr[2] + sr[3];
        float T = sr[4] + sr[5] + sr[6] + sr[7];
        acc[plane] = S / T;
    }
}

__global__ void final_kernel(const float* __restrict__ acc, float* __restrict__ out) {
    int lane = threadIdx.x;
    float r = (lane < NBC) ? acc[lane] : 0.0f;
    #pragma unroll
    for (int d = 1; d < 64; d <<= 1) r += __shfl_xor(r, d);
    if (lane == 0) out[0] = r / (float)NBC;
}

extern "C" void kernel_launch(void* const* d_in, const int* in_sizes, int n_in,
                              void* d_out, int out_size, void* d_ws, size_t ws_size,
                              hipStream_t stream) {
    const float* correct  = (const float*)d_in[0];
    const float* estimate = (const float*)d_in[1];
    const float* mask     = (const float*)d_in[2];
    float* out = (float*)d_out;

    float* acc   = (float*)d_ws;                 // 48 floats
    float* tiles = (float*)d_ws + 64;            // 48*51*51*3 floats ≈ 1.5 MB

    tile_kernel<<<NBC * NT, 256, 0, stream>>>(correct, estimate, mask, tiles);
    window_kernel<<<NBC, 256, 0, stream>>>(tiles, acc);
    final_kernel<<<1, 64, 0, stream>>>(acc, out);
}

// Round 3
// 35.565 us; speedup vs baseline: 2.1811x; 1.0046x over previous
//
#include <hip/hip_runtime.h>
#include <hip/hip_bf16.h>

#define HWDIM 512
#define NWIN 50        // windows per dim: (512-20)/10 + 1
#define NT 51          // 10x10 tiles per dim covering rows/cols 0..509
#define NBC 48         // B*C = 16*3
#define EPSV 1e-5f

// ---------------------------------------------------------------------------
// Pass 1: per-(plane, 10-row stripe) tile sums, float4 loads, batched MLP.
// Thread t: col4 = t&127 (cols 4*col4 .. 4*col4+3), row-half rh = t>>7.
// Rows processed: 2*it + rh, it = 0..4  (covers the stripe's 10 rows).
// Tile split: pattern repeats every 5 float4s (20 cols = 2 tiles);
// f = col4 % 5: f=0,1 -> all 4 cols in tile 2k; f=2 -> cols 0,1 in tile 2k,
// cols 2,3 in tile 2k+1; f=3,4 -> all 4 in tile 2k+1.  (k = col4/5)
// Output: tiles[(blk*NT + tx)*3 + {0,1,2}] = (sum m*c*c, m*c*e, m*e*e).
// ---------------------------------------------------------------------------
__global__ __launch_bounds__(256) void tile_kernel(const float* __restrict__ C,
                                                   const float* __restrict__ E,
                                                   const float* __restrict__ M,
                                                   float* __restrict__ tiles) {
    int blk   = blockIdx.x;        // plane*NT + ty
    int plane = blk / NT;
    int ty    = blk % NT;
    int t     = threadIdx.x;
    int c4    = t & 127;
    int rh    = t >> 7;
    int f     = c4 % 5;
    bool isf2 = (f == 2);

    size_t base = ((size_t)plane * HWDIM + (size_t)ty * 10 + rh) * HWDIM + 4 * c4;

    // batch all 15 loads -> max memory-level parallelism
    float4 cv[5], ev[5], mv[5];
    #pragma unroll
    for (int it = 0; it < 5; ++it) {
        size_t o = base + (size_t)(2 * it) * HWDIM;
        cv[it] = *(const float4*)(C + o);
        ev[it] = *(const float4*)(E + o);
        mv[it] = *(const float4*)(M + o);
    }

    // accumulate element-pairs (0,1) and (2,3) separately; split at the end
    float s01[3] = {0.f, 0.f, 0.f};
    float s23[3] = {0.f, 0.f, 0.f};
    #pragma unroll
    for (int it = 0; it < 5; ++it) {
        float4 c = cv[it], e = ev[it], m = mv[it];
        float mcx = m.x * c.x, mcy = m.y * c.y, mcz = m.z * c.z, mcw = m.w * c.w;
        float mex = m.x * e.x, mey = m.y * e.y, mez = m.z * e.z, mew = m.w * e.w;
        s01[0] = fmaf(mcx, c.x, s01[0]); s01[0] = fmaf(mcy, c.y, s01[0]);
        s01[1] = fmaf(mcx, e.x, s01[1]); s01[1] = fmaf(mcy, e.y, s01[1]);
        s01[2] = fmaf(mex, e.x, s01[2]); s01[2] = fmaf(mey, e.y, s01[2]);
        s23[0] = fmaf(mcz, c.z, s23[0]); s23[0] = fmaf(mcw, c.w, s23[0]);
        s23[1] = fmaf(mcz, e.z, s23[1]); s23[1] = fmaf(mcw, e.w, s23[1]);
        s23[2] = fmaf(mez, e.z, s23[2]); s23[2] = fmaf(mew, e.w, s23[2]);
    }

    __shared__ float lds[256 * 6];
    #pragma unroll
    for (int comp = 0; comp < 3; ++comp) {
        float lo = s01[comp] + (isf2 ? 0.f : s23[comp]);
        float hi = isf2 ? s23[comp] : 0.f;
        lds[t * 6 + comp]     = lo;
        lds[t * 6 + 3 + comp] = hi;
    }
    __syncthreads();

    if (t < NT * 3) {              // 153 threads: one per (tile, component)
        int tx = t / 3, comp = t % 3;
        int k  = tx >> 1;
        float s;
        if ((tx & 1) == 0) {
            int b = 5 * k;
            s = lds[b * 6 + comp] + lds[(b + 1) * 6 + comp] + lds[(b + 2) * 6 + comp]
              + lds[(b + 128) * 6 + comp] + lds[(b + 129) * 6 + comp] + lds[(b + 130) * 6 + comp];
        } else {
            int b = 5 * k + 2;
            s = lds[b * 6 + 3 + comp] + lds[(b + 1) * 6 + comp] + lds[(b + 2) * 6 + comp]
              + lds[(b + 128) * 6 + 3 + comp] + lds[(b + 129) * 6 + comp] + lds[(b + 130) * 6 + comp];
        }
        tiles[((size_t)blk * NT + tx) * 3 + comp] = s;
    }
}

// ---------------------------------------------------------------------------
// Pass 2: per-plane window combine. Window (wy,wx) = 4 tiles.
// ---------------------------------------------------------------------------
__global__ __launch_bounds__(256) void window_kernel(const float* __restrict__ tiles,
                                                     float* __restrict__ acc) {
    int plane = blockIdx.x;
    const float* tp = tiles + (size_t)plane * NT * NT * 3;

    float ssq = 0.0f, tot = 0.0f;
    for (int w = threadIdx.x; w < NWIN * NWIN; w += 256) {
        int wy = w / NWIN, wx = w % NWIN;
        const float* t00 = tp + ((size_t)wy * NT + wx) * 3;
        const float* t10 = t00 + (size_t)NT * 3;
        float s_cc = t00[0] + t00[3] + t10[0] + t10[3];
        float s_ce = t00[1] + t00[4] + t10[1] + t10[4];
        float s_ee = t00[2] + t00[5] + t10[2] + t10[5];
        float a2v = (s_ee > EPSV) ? (s_ce * s_ce / s_ee) : 0.0f;
        ssq += s_cc - a2v;
        tot += s_cc;
    }

    #pragma unroll
    for (int d = 1; d < 64; d <<= 1) {
        ssq += __shfl_xor(ssq, d);
        tot += __shfl_xor(tot, d);
    }
    __shared__ float sr[8];
    int lane = threadIdx.x & 63, wave = threadIdx.x >> 6;
    if (lane == 0) { sr[wave] = ssq; sr[4 + wave] = tot; }
    __syncthreads();
    if (threadIdx.x == 0) {
        float S = sr[0] + sr[1] + sr[2] + sr[3];
        float T = sr[4] + sr[5] + sr[6] + sr[7];
        acc[plane] = S / T;
    }
}

__global__ void final_kernel(const float* __restrict__ acc, float* __restrict__ out) {
    int lane = threadIdx.x;
    float r = (lane < NBC) ? acc[lane] : 0.0f;
    #pragma unroll
    for (int d = 1; d < 64; d <<= 1) r += __shfl_xor(r, d);
    if (lane == 0) out[0] = r / (float)NBC;
}

extern "C" void kernel_launch(void* const* d_in, const int* in_sizes, int n_in,
                              void* d_out, int out_size, void* d_ws, size_t ws_size,
                              hipStream_t stream) {
    const float* correct  = (const float*)d_in[0];
    const float* estimate = (const float*)d_in[1];
    const float* mask     = (const float*)d_in[2];
    float* out = (float*)d_out;

    float* acc   = (float*)d_ws;                 // 48 floats
    float* tiles = (float*)d_ws + 64;            // 48*51*51*3 floats ≈ 1.5 MB

    tile_kernel<<<NBC * NT, 256, 0, stream>>>(correct, estimate, mask, tiles);
    window_kernel<<<NBC, 256, 0, stream>>>(tiles, acc);
    final_kernel<<<1, 64, 0, stream>>>(acc, out);
}